// Round 1
// baseline (589.068 us; speedup 1.0000x reference)
//
#include <hip/hip_runtime.h>
#include <hip/hip_bf16.h>
#include <math.h>

typedef __bf16 bf16;
typedef __bf16 bf16x4 __attribute__((ext_vector_type(4)));
typedef __bf16 bf16x8 __attribute__((ext_vector_type(8)));
typedef float f32x4 __attribute__((ext_vector_type(4)));

#define MFMA(a, b, c) __builtin_amdgcn_mfma_f32_16x16x32_bf16((a), (b), (c), 0, 0, 0)

// Problem constants (fixed by the reference setup_inputs)
constexpr int Bb  = 2;
constexpr int Hh  = 16;
constexpr int Ss  = 2048;
constexpr int KVv = 4096;
constexpr int Dd  = 64;
constexpr int Cc  = KVv - Ss;   // 2048
constexpr int HID = Hh * Dd;    // 1024

// ---------------------------------------------------------------------------
// Attention: one block = (b,h) x 64 q-rows. 4 waves, each owns 16 q-rows.
// K tile [64kv x 64d] bf16 in LDS; V tile stored transposed [64d x 64kv].
// QK^T via mfma(A=Q, B=K^T); P routed through LDS to become the A operand of PV.
// Online softmax with per-row (m,l) replicated across each 16-lane group.
// ---------------------------------------------------------------------------
__global__ __launch_bounds__(256) void attn_kernel(
    const float* __restrict__ q, const float* __restrict__ k,
    const float* __restrict__ v, const int* __restrict__ memp,
    bf16* __restrict__ attnb)
{
    __shared__ __align__(16) bf16 Klds[64][72];
    __shared__ __align__(16) bf16 Vt[64][72];     // Vt[d][kv]
    __shared__ __align__(16) bf16 Plds[4][16][72];

    const int tid = threadIdx.x;
    const int w  = tid >> 6;
    const int l  = tid & 63;
    const int lr = l & 15;
    const int lg = l >> 4;
    const int bh = blockIdx.y;
    const int q0 = blockIdx.x * 64;
    const int mem = *memp;
    const int R = Cc + mem;

    const float* qp = q + (size_t)bh * Ss * Dd;
    const float* kp = k + (size_t)bh * KVv * Dd;
    const float* vp = v + (size_t)bh * KVv * Dd;

    // Q fragments (A operand): lane holds Q[q0+w*16+lr][ks*32 + lg*8 + j]
    const int qrow = q0 + w * 16 + lr;
    bf16x8 qa[2];
#pragma unroll
    for (int ks = 0; ks < 2; ++ks) {
        const float* p8 = qp + (size_t)qrow * Dd + ks * 32 + lg * 8;
        float4 x0 = *(const float4*)p8;
        float4 x1 = *(const float4*)(p8 + 4);
        bf16x8 a;
        a[0] = (bf16)x0.x; a[1] = (bf16)x0.y; a[2] = (bf16)x0.z; a[3] = (bf16)x0.w;
        a[4] = (bf16)x1.x; a[5] = (bf16)x1.y; a[6] = (bf16)x1.z; a[7] = (bf16)x1.w;
        qa[ks] = a;
    }

    f32x4 acco[4];
#pragma unroll
    for (int dg = 0; dg < 4; ++dg) acco[dg] = (f32x4){0.f, 0.f, 0.f, 0.f};
    float m_r[4] = {-__builtin_inff(), -__builtin_inff(), -__builtin_inff(), -__builtin_inff()};
    float l_r[4] = {0.f, 0.f, 0.f, 0.f};

    // Tile skip: columns >= kv_end are masked for every row in this q-tile.
    const int qmax = q0 + 63;
    int maxcol = (qmax < mem) ? (R - 1)
                              : ((qmax + Cc > R - 1) ? (qmax + Cc) : (R - 1));
    int kv_end = maxcol + 1;
    if (kv_end > KVv) kv_end = KVv;

    for (int t0 = 0; t0 < kv_end; t0 += 64) {
        // ---- stage K tile (row-major, fp32 -> bf16) ----
#pragma unroll
        for (int it = 0; it < 4; ++it) {
            int idx = it * 256 + tid;
            int row = idx >> 4, c4 = idx & 15;
            float4 x = *(const float4*)(kp + (size_t)(t0 + row) * Dd + c4 * 4);
            bf16x4 t;
            t[0] = (bf16)x.x; t[1] = (bf16)x.y; t[2] = (bf16)x.z; t[3] = (bf16)x.w;
            *(bf16x4*)&Klds[row][c4 * 4] = t;
        }
        // ---- stage V transposed: thread loads rows 4r..4r+3, col c4*4..+3 ----
        {
            int r = tid & 15, c4 = tid >> 4;
            const float* vb = vp + (size_t)(t0 + r * 4) * Dd + c4 * 4;
            float4 a0 = *(const float4*)(vb);
            float4 a1 = *(const float4*)(vb + Dd);
            float4 a2 = *(const float4*)(vb + 2 * Dd);
            float4 a3 = *(const float4*)(vb + 3 * Dd);
            const float* f0 = (const float*)&a0;
            const float* f1 = (const float*)&a1;
            const float* f2 = (const float*)&a2;
            const float* f3 = (const float*)&a3;
#pragma unroll
            for (int i = 0; i < 4; ++i) {
                bf16x4 t;
                t[0] = (bf16)f0[i]; t[1] = (bf16)f1[i];
                t[2] = (bf16)f2[i]; t[3] = (bf16)f3[i];
                *(bf16x4*)&Vt[c4 * 4 + i][r * 4] = t;
            }
        }
        __syncthreads();

        // ---- QK^T: acc_s[kg] = Q(16x64) . K^T(64x16) for key group kg ----
        f32x4 accs[4];
#pragma unroll
        for (int kg = 0; kg < 4; ++kg) accs[kg] = (f32x4){0.f, 0.f, 0.f, 0.f};
#pragma unroll
        for (int ks = 0; ks < 2; ++ks) {
#pragma unroll
            for (int kg = 0; kg < 4; ++kg) {
                bf16x8 kb = *(const bf16x8*)&Klds[kg * 16 + lr][ks * 32 + lg * 8];
                accs[kg] = MFMA(qa[ks], kb, accs[kg]);
            }
        }

        // ---- mask + online softmax (C layout: col=lr -> key, row=lg*4+r -> q) ----
        float corr[4];
#pragma unroll
        for (int r = 0; r < 4; ++r) {
            int qabs = q0 + w * 16 + lg * 4 + r;
#pragma unroll
            for (int kg = 0; kg < 4; ++kg) {
                float s = accs[kg][r] * 0.125f;
                int tcol = t0 + kg * 16 + lr;
                bool msk = (tcol >= R) && ((qabs < mem) || (tcol - R > qabs - mem));
                accs[kg][r] = msk ? -__builtin_inff() : s;
            }
            float mx = fmaxf(fmaxf(accs[0][r], accs[1][r]), fmaxf(accs[2][r], accs[3][r]));
            mx = fmaxf(mx, __shfl_xor(mx, 1));
            mx = fmaxf(mx, __shfl_xor(mx, 2));
            mx = fmaxf(mx, __shfl_xor(mx, 4));
            mx = fmaxf(mx, __shfl_xor(mx, 8));
            float nm = fmaxf(m_r[r], mx);
            corr[r] = __expf(m_r[r] - nm);   // first tile: exp(-inf) = 0
            float sum = 0.f;
#pragma unroll
            for (int kg = 0; kg < 4; ++kg) {
                float p = __expf(accs[kg][r] - nm);  // masked: exp(-inf)=0
                accs[kg][r] = p;
                sum += p;
            }
            sum += __shfl_xor(sum, 1);
            sum += __shfl_xor(sum, 2);
            sum += __shfl_xor(sum, 4);
            sum += __shfl_xor(sum, 8);
            l_r[r] = l_r[r] * corr[r] + sum;
            m_r[r] = nm;
#pragma unroll
            for (int kg = 0; kg < 4; ++kg)
                Plds[w][lg * 4 + r][kg * 16 + lr] = (bf16)accs[kg][r];
        }
        asm volatile("s_waitcnt lgkmcnt(0)" ::: "memory");

        // ---- rescale O, then PV: O += P(16x64) . V(64x64) ----
#pragma unroll
        for (int dg = 0; dg < 4; ++dg)
#pragma unroll
            for (int r = 0; r < 4; ++r) acco[dg][r] *= corr[r];
#pragma unroll
        for (int ks = 0; ks < 2; ++ks) {
            bf16x8 pa = *(const bf16x8*)&Plds[w][lr][ks * 32 + lg * 8];
#pragma unroll
            for (int dg = 0; dg < 4; ++dg) {
                bf16x8 vbf = *(const bf16x8*)&Vt[dg * 16 + lr][ks * 32 + lg * 8];
                acco[dg] = MFMA(pa, vbf, acco[dg]);
            }
        }
        __syncthreads();
    }

    // ---- epilogue: attn[b][s][h*64+d] = O / l, stored bf16 ----
    const int b = bh >> 4, h = bh & 15;
#pragma unroll
    for (int r = 0; r < 4; ++r) {
        float inv = 1.f / l_r[r];
        int qabs = q0 + w * 16 + lg * 4 + r;
        bf16* dst = attnb + (size_t)(b * Ss + qabs) * HID + h * Dd;
#pragma unroll
        for (int dg = 0; dg < 4; ++dg)
            dst[dg * 16 + lr] = (bf16)(acco[dg][r] * inv);
    }
}

// ---------------------------------------------------------------------------
// Projection: out[4096,1024] = attn_bf16[4096,1024] @ W^T + b   (fp32 out)
// ---------------------------------------------------------------------------
__global__ __launch_bounds__(256) void proj_kernel(
    const bf16* __restrict__ A, const float* __restrict__ W,
    const float* __restrict__ bias, float* __restrict__ out)
{
    __shared__ __align__(16) bf16 Alds[64][72];
    __shared__ __align__(16) bf16 Wlds[64][72];

    const int tid = threadIdx.x;
    const int w  = tid >> 6;
    const int l  = tid & 63;
    const int lr = l & 15;
    const int lg = l >> 4;
    const int o0 = blockIdx.x * 64;
    const int i0 = blockIdx.y * 64;

    f32x4 acc[4];
#pragma unroll
    for (int og = 0; og < 4; ++og) acc[og] = (f32x4){0.f, 0.f, 0.f, 0.f};

    for (int kc = 0; kc < HID; kc += 64) {
        // stage A (already bf16)
#pragma unroll
        for (int it = 0; it < 2; ++it) {
            int idx = it * 256 + tid;
            int row = idx >> 3, c8 = idx & 7;
            bf16x8 x = *(const bf16x8*)(A + (size_t)(i0 + row) * HID + kc + c8 * 8);
            *(bf16x8*)&Alds[row][c8 * 8] = x;
        }
        // stage W (fp32 -> bf16), rows are output channels
#pragma unroll
        for (int it = 0; it < 4; ++it) {
            int idx = it * 256 + tid;
            int row = idx >> 4, c4 = idx & 15;
            float4 x = *(const float4*)(W + (size_t)(o0 + row) * HID + kc + c4 * 4);
            bf16x4 t;
            t[0] = (bf16)x.x; t[1] = (bf16)x.y; t[2] = (bf16)x.z; t[3] = (bf16)x.w;
            *(bf16x4*)&Wlds[row][c4 * 4] = t;
        }
        __syncthreads();
#pragma unroll
        for (int ks = 0; ks < 2; ++ks) {
            bf16x8 af = *(const bf16x8*)&Alds[w * 16 + lr][ks * 32 + lg * 8];
#pragma unroll
            for (int og = 0; og < 4; ++og) {
                bf16x8 wf = *(const bf16x8*)&Wlds[og * 16 + lr][ks * 32 + lg * 8];
                acc[og] = MFMA(af, wf, acc[og]);
            }
        }
        __syncthreads();
    }

#pragma unroll
    for (int r = 0; r < 4; ++r) {
        int i = i0 + w * 16 + lg * 4 + r;
#pragma unroll
        for (int og = 0; og < 4; ++og) {
            int o = o0 + og * 16 + lr;
            out[(size_t)i * HID + o] = acc[og][r] + bias[o];
        }
    }
}

// ---------------------------------------------------------------------------
// Mask: mask[b][h][s][t] = (t >= thr(s)) with thr = (s<mem)? C+mem : s+C+1
// ---------------------------------------------------------------------------
__global__ __launch_bounds__(256) void mask_kernel(
    float* __restrict__ mout, const int* __restrict__ memp)
{
    const int mem = *memp;
    const int R = Cc + mem;
    const size_t total4 = (size_t)Bb * Hh * Ss * KVv / 4;
    const size_t stride = (size_t)gridDim.x * blockDim.x;
    for (size_t i = (size_t)blockIdx.x * blockDim.x + threadIdx.x; i < total4; i += stride) {
        size_t flat = i * 4;
        int t = (int)(flat & (size_t)(KVv - 1));
        int s = (int)((flat >> 12) & (size_t)(Ss - 1));
        int thr = (s < mem) ? R : (s + Cc + 1);
        float4 vv;
        vv.x = (float)(t >= thr);
        vv.y = (float)(t + 1 >= thr);
        vv.z = (float)(t + 2 >= thr);
        vv.w = (float)(t + 3 >= thr);
        *(float4*)(mout + flat) = vv;
    }
}

extern "C" void kernel_launch(void* const* d_in, const int* in_sizes, int n_in,
                              void* d_out, int out_size, void* d_ws, size_t ws_size,
                              hipStream_t stream)
{
    (void)in_sizes; (void)n_in; (void)out_size; (void)d_ws; (void)ws_size;
    const float* q    = (const float*)d_in[0];
    const float* k    = (const float*)d_in[1];
    const float* v    = (const float*)d_in[2];
    const int*   memp = (const int*)d_in[3];
    const float* W    = (const float*)d_in[4];
    const float* bias = (const float*)d_in[5];

    float* out     = (float*)d_out;
    float* maskout = out + (size_t)Bb * Ss * HID;   // mask region starts after out
    bf16*  attnb   = (bf16*)maskout;                // scratch carved from mask region
                                                    // (overwritten by mask_kernel last)

    attn_kernel<<<dim3(Ss / 64, Bb * Hh), 256, 0, stream>>>(q, k, v, memp, attnb);
    proj_kernel<<<dim3(HID / 64, (Bb * Ss) / 64), 256, 0, stream>>>(attnb, W, bias, out);
    mask_kernel<<<dim3(2048), 256, 0, stream>>>(maskout, memp);
}